// Round 12
// baseline (148.208 us; speedup 1.0000x reference)
//
#include <hip/hip_runtime.h>

#define DD 256
#define BB 8
#define SS 1024
#define XSTRIDE 264   // f16 elems per LDS row (528 B, 16B-aligned)

// ws layout per layer (bytes): Mtab 131072 | Ptab 131072 | Itab 262144 = 524288
#define LAYER_BYTES 524288
#define PTAB_OFF    131072
#define ITAB_OFF    262144
#define WS_NEEDED   (2 * LAYER_BYTES)

typedef _Float16 half8  __attribute__((ext_vector_type(8)));
typedef _Float16 half2t __attribute__((ext_vector_type(2)));
typedef __fp16   fp16x2 __attribute__((ext_vector_type(2)));
typedef __attribute__((ext_vector_type(4))) float float4v;

__device__ __forceinline__ half2t pkrtz(float a, float b) {
    union { fp16x2 f; half2t h; } cv;
    cv.f = __builtin_amdgcn_cvt_pkrtz(a, b);
    return cv.h;
}

// Fragment-ordered tables: gi = (kt*16 + wt)*64 + lane, lane = quad*16+l15,
// n = 16*wt + l15, j0 = kt*32 + quad*8:
//   Mtab[gi] = M[n][j0..j0+7] f16, Ptab[gi] = P[n][j0..j0+7] f16,
//   Itab[2gi..] = 1/(n*256 + j0 + e + 2) f32, e=0..7
__global__ void build_tabs(const float* __restrict__ M1, const float* __restrict__ P1,
                           const float* __restrict__ M2, const float* __restrict__ P2,
                           char* __restrict__ ws)
{
    int gid   = blockIdx.x * 256 + threadIdx.x;   // 0..16383
    int layer = gid >> 13;
    int gi    = gid & 8191;
    int idx   = gi >> 6;
    int lane  = gi & 63;
    int kt    = idx >> 4;
    int wt    = idx & 15;
    int l15   = lane & 15, quad = lane >> 4;
    int n     = 16 * wt + l15;
    int j0    = kt * 32 + quad * 8;

    const float* Msrc = layer ? M2 : M1;
    const float* Psrc = layer ? P2 : P1;

    union { half8 h; half2t h2[4]; } mh, ph;
    float iv[8];
    #pragma unroll
    for (int e = 0; e < 4; ++e) {
        float ma = Msrc[(size_t)n * DD + j0 + 2 * e];
        float mb = Msrc[(size_t)n * DD + j0 + 2 * e + 1];
        float pa = Psrc[(size_t)n * DD + j0 + 2 * e];
        float pb = Psrc[(size_t)n * DD + j0 + 2 * e + 1];
        mh.h2[e] = pkrtz(ma, mb);
        ph.h2[e] = pkrtz(pa, pb);
        iv[2 * e]     = 1.0f / (float)(n * DD + j0 + 2 * e + 2);
        iv[2 * e + 1] = 1.0f / (float)(n * DD + j0 + 2 * e + 3);
    }
    char* base = ws + (size_t)layer * LAYER_BYTES;
    ((half8*)base)[gi]              = mh.h;
    ((half8*)(base + PTAB_OFF))[gi] = ph.h;
    float4* it = (float4*)(base + ITAB_OFF);
    it[2 * gi]     = make_float4(iv[0], iv[1], iv[2], iv[3]);
    it[2 * gi + 1] = make_float4(iv[4], iv[5], iv[6], iv[7]);
}

// Block = 1024 threads (16 waves), s-pair (s0,s0+1) per block, grid 512.
// Wave w owns ONE n-tile (n = 16w + l15). Residual in registers.
// KEY: phi = cos(2*pi*k/periods) is LAYER-INVARIANT -> computed in layer 0,
// cached as packed f16 pairs in 64 VGPRs, reused bit-identically in layer 1
// (today's path already rounds cos to f16 before the P multiply).
template<bool TABS>
__global__ __launch_bounds__(1024, 4)
void fused_hierddpm(const float* __restrict__ seq,
                    const float* __restrict__ M1, const float* __restrict__ P1,
                    const float* __restrict__ g1, const float* __restrict__ be1,
                    const float* __restrict__ M2, const float* __restrict__ P2,
                    const float* __restrict__ g2, const float* __restrict__ be2,
                    const char* __restrict__ ws,
                    float* __restrict__ out)
{
    __shared__ __align__(16) _Float16 xsb[16][XSTRIDE]; // input / layer-out, f16, A-layout
    __shared__ __align__(16) _Float16 xtb[16][XSTRIDE]; // LN'd xt, f16
    __shared__ float stats[16][16][2];

    const int tid  = threadIdx.x;
    const int w    = tid >> 6;          // wave id 0..15 == owned n-tile
    const int lane = tid & 63;
    const int l15  = lane & 15;
    const int quad = lane >> 4;
    const int s0   = blockIdx.x * 2;
    const float k0 = (float)s0, k1 = (float)(s0 + 1);
    const int col  = 16 * w + l15;      // this lane's output column

    // cos cache: cc0/cc1[kt][e] = f16-pair cos for s0/s1 (static indices only!)
    half2t cc0[8][4], cc1[8][4];

    // ---- stage x into xsb (f16, rows r = sl*8+b), coalesced float4 reads
    {
        const float4* seq4 = (const float4*)seq;
        int v  = tid;                   // float4 index 0..1023
        int sl = v >> 9;
        int rm = v & 511;
        int b  = rm >> 6, j4 = rm & 63;
        float4 x = seq4[((size_t)b * SS + s0 + sl) * 64 + j4];
        half2t* dst = (half2t*)&xsb[sl * 8 + b][4 * j4];
        dst[0] = pkrtz(x.x, x.y);
        dst[1] = pkrtz(x.z, x.w);
    }

    // ---- residual in registers: res[reg] for (sl=quad>>1, b=(quad*4+reg)&7, col)
    float res[4];
    {
        const int sl = quad >> 1;
        #pragma unroll
        for (int reg = 0; reg < 4; ++reg) {
            int b = (quad * 4 + reg) & 7;
            res[reg] = seq[((size_t)b * SS + s0 + sl) * DD + col];
        }
    }
    __syncthreads();

    #pragma unroll 1
    for (int layer = 0; layer < 2; ++layer) {
        const float* M  = layer ? M2  : M1;
        const float* P  = layer ? P2  : P1;
        const float* g  = layer ? g2  : g1;
        const float* be = layer ? be2 : be1;
        const char*  lbase = ws + (size_t)layer * LAYER_BYTES;
        const half8*  Mtab = (const half8*)lbase;
        const half8*  Ptab = (const half8*)(lbase + PTAB_OFF);
        const float4* Itab = (const float4*)(lbase + ITAB_OFF);

        // ======== phase A: xt = x @ M^T (f16 MFMA); wave owns n-tile w
        float4v acc1 = (float4v){0.f, 0.f, 0.f, 0.f};

        #pragma unroll 2
        for (int kt = 0; kt < 8; ++kt) {
            half8 a = *(const half8*)&xsb[l15][kt * 32 + quad * 8];
            half8 bfrag;
            if (TABS) {
                bfrag = Mtab[(kt * 16 + w) * 64 + lane];
            } else {
                int n = 16 * w + l15;
                const float4* Mr = (const float4*)M +
                    ((size_t)n * 64 + kt * 8 + quad * 2);
                float4 m0 = Mr[0], m1 = Mr[1];
                union { half8 h; half2t h2[4]; } bb;
                bb.h2[0] = pkrtz(m0.x, m0.y);
                bb.h2[1] = pkrtz(m0.z, m0.w);
                bb.h2[2] = pkrtz(m1.x, m1.y);
                bb.h2[3] = pkrtz(m1.z, m1.w);
                bfrag = bb.h;
            }
            acc1 = __builtin_amdgcn_mfma_f32_16x16x32_f16(a, bfrag, acc1, 0, 0, 0);
        }

        // ======== LayerNorm in C-register layout (row m = quad*4+reg)
        {
            #pragma unroll
            for (int reg = 0; reg < 4; ++reg) {
                float sm = acc1[reg];
                float sq = acc1[reg] * acc1[reg];
                #pragma unroll
                for (int off = 1; off < 16; off <<= 1) {
                    sm += __shfl_xor(sm, off, 64);
                    sq += __shfl_xor(sq, off, 64);
                }
                if (l15 == 0) {
                    stats[w][quad * 4 + reg][0] = sm;
                    stats[w][quad * 4 + reg][1] = sq;
                }
            }
        }
        __syncthreads();
        {
            float mu[4], rs[4];
            #pragma unroll
            for (int reg = 0; reg < 4; ++reg) {
                int m = quad * 4 + reg;
                float sm = 0.f, sq = 0.f;
                #pragma unroll
                for (int ww = 0; ww < 16; ++ww) {
                    sm += stats[ww][m][0];
                    sq += stats[ww][m][1];
                }
                float mm = sm * (1.f / DD);
                mu[reg] = mm;
                rs[reg] = rsqrtf(sq * (1.f / DD) - mm * mm + 1e-5f);
            }
            float gv = g[col], bv = be[col];
            #pragma unroll
            for (int reg = 0; reg < 4; ++reg) {
                float v = fmaf((acc1[reg] - mu[reg]) * rs[reg], gv, bv);
                xtb[quad * 4 + reg][col] = (_Float16)v;
            }
        }
        __syncthreads();   // xtb ready for phase B

        // ======== phase B: Nk = xt @ W_s^T
        float4v accS[2];
        accS[0] = (float4v){0.f, 0.f, 0.f, 0.f};
        accS[1] = (float4v){0.f, 0.f, 0.f, 0.f};

        if (layer == 0) {
            // compute cos chain, cache f16 pairs, FMA into accS
            #pragma unroll
            for (int kt = 0; kt < 8; ++kt) {
                half8 a = *(const half8*)&xtb[l15][kt * 32 + quad * 8];
                union { half8 h; half2t h2[4]; } pv;
                float iv[8];
                if (TABS) {
                    int gi = (kt * 16 + w) * 64 + lane;
                    pv.h = Ptab[gi];
                    float4 i0 = Itab[2 * gi], i1 = Itab[2 * gi + 1];
                    iv[0] = i0.x; iv[1] = i0.y; iv[2] = i0.z; iv[3] = i0.w;
                    iv[4] = i1.x; iv[5] = i1.y; iv[6] = i1.z; iv[7] = i1.w;
                } else {
                    int n = 16 * w + l15;
                    const float4* Pr = (const float4*)P +
                        ((size_t)n * 64 + kt * 8 + quad * 2);
                    float4 p0 = Pr[0], p1 = Pr[1];
                    pv.h2[0] = pkrtz(p0.x, p0.y);
                    pv.h2[1] = pkrtz(p0.z, p0.w);
                    pv.h2[2] = pkrtz(p1.x, p1.y);
                    pv.h2[3] = pkrtz(p1.z, p1.w);
                    float pbase = (float)(n * DD + kt * 32 + quad * 8 + 2);
                    #pragma unroll
                    for (int e = 0; e < 8; ++e)
                        iv[e] = __builtin_amdgcn_rcpf(pbase + (float)e);
                }
                union { half8 h; half2t h2[4]; } b0, b1;
                #pragma unroll
                for (int e = 0; e < 4; ++e) {
                    float ia = iv[2 * e], ib = iv[2 * e + 1];
                    half2t c0 = pkrtz(
                        __builtin_amdgcn_cosf(__builtin_amdgcn_fractf(k0 * ia)),
                        __builtin_amdgcn_cosf(__builtin_amdgcn_fractf(k0 * ib)));
                    half2t c1 = pkrtz(
                        __builtin_amdgcn_cosf(__builtin_amdgcn_fractf(k1 * ia)),
                        __builtin_amdgcn_cosf(__builtin_amdgcn_fractf(k1 * ib)));
                    cc0[kt][e] = c0;
                    cc1[kt][e] = c1;
                    b0.h2[e] = pv.h2[e] * c0;   // v_pk_mul_f16
                    b1.h2[e] = pv.h2[e] * c1;
                }
                accS[0] = __builtin_amdgcn_mfma_f32_16x16x32_f16(a, b0.h, accS[0], 0, 0, 0);
                accS[1] = __builtin_amdgcn_mfma_f32_16x16x32_f16(a, b1.h, accS[1], 0, 0, 0);
            }
        } else {
            // reuse cached cos (bit-identical): loads + pk_mul + MFMA only
            #pragma unroll
            for (int kt = 0; kt < 8; ++kt) {
                half8 a = *(const half8*)&xtb[l15][kt * 32 + quad * 8];
                union { half8 h; half2t h2[4]; } pv;
                if (TABS) {
                    pv.h = Ptab[(kt * 16 + w) * 64 + lane];
                } else {
                    int n = 16 * w + l15;
                    const float4* Pr = (const float4*)P +
                        ((size_t)n * 64 + kt * 8 + quad * 2);
                    float4 p0 = Pr[0], p1 = Pr[1];
                    pv.h2[0] = pkrtz(p0.x, p0.y);
                    pv.h2[1] = pkrtz(p0.z, p0.w);
                    pv.h2[2] = pkrtz(p1.x, p1.y);
                    pv.h2[3] = pkrtz(p1.z, p1.w);
                }
                union { half8 h; half2t h2[4]; } b0, b1;
                #pragma unroll
                for (int e = 0; e < 4; ++e) {
                    b0.h2[e] = pv.h2[e] * cc0[kt][e];
                    b1.h2[e] = pv.h2[e] * cc1[kt][e];
                }
                accS[0] = __builtin_amdgcn_mfma_f32_16x16x32_f16(a, b0.h, accS[0], 0, 0, 0);
                accS[1] = __builtin_amdgcn_mfma_f32_16x16x32_f16(a, b1.h, accS[1], 0, 0, 0);
            }
        }

        // ======== epilogue: pick valid s-half per quad, add register residual
        {
            float4v av = (quad < 2) ? accS[0] : accS[1];
            int sl = quad >> 1;
            #pragma unroll
            for (int reg = 0; reg < 4; ++reg) {
                int m = quad * 4 + reg;
                int b = m & 7;
                float val = av[reg] + res[reg];
                if (layer == 0) {
                    res[reg]    = val;             // next layer's residual
                    xsb[m][col] = (_Float16)val;   // next layer's A-matrix
                } else {
                    out[((size_t)b * SS + s0 + sl) * DD + col] = val;
                }
            }
        }
        if (layer == 0) __syncthreads();
    }
}

extern "C" void kernel_launch(void* const* d_in, const int* in_sizes, int n_in,
                              void* d_out, int out_size, void* d_ws, size_t ws_size,
                              hipStream_t stream)
{
    const float* seq = (const float*)d_in[0];
    const float* M1  = (const float*)d_in[1];
    const float* P1  = (const float*)d_in[2];
    const float* g1  = (const float*)d_in[3];
    const float* b1  = (const float*)d_in[4];
    const float* M2  = (const float*)d_in[5];
    const float* P2  = (const float*)d_in[6];
    const float* g2  = (const float*)d_in[7];
    const float* b2  = (const float*)d_in[8];
    float* out = (float*)d_out;

    if (ws_size >= WS_NEEDED) {
        build_tabs<<<64, 256, 0, stream>>>(M1, P1, M2, P2, (char*)d_ws);
        fused_hierddpm<true><<<SS / 2, 1024, 0, stream>>>(
            seq, M1, P1, g1, b1, M2, P2, g2, b2, (const char*)d_ws, out);
    } else {
        fused_hierddpm<false><<<SS / 2, 1024, 0, stream>>>(
            seq, M1, P1, g1, b1, M2, P2, g2, b2, nullptr, out);
    }
}

// Round 13
// 118.189 us; speedup vs baseline: 1.2540x; 1.2540x over previous
//
#include <hip/hip_runtime.h>

#define DD 256
#define BB 8
#define SS 1024
#define XSTRIDE 264   // f16 elems per LDS row (528 B, 16B-aligned)

// ws layout per layer (bytes): Mtab 131072 | Ptab 131072 | Jtab 262144 = 524288
#define LAYER_BYTES 524288
#define PTAB_OFF    131072
#define JTAB_OFF    262144
#define WS_NEEDED   (2 * LAYER_BYTES)

#define TWO_PI 6.28318530717958647692f
#define PBMIN  640.0f   // rotation approx valid for p0 >= 640 (err <= ~2.2e-4)

typedef _Float16 half8  __attribute__((ext_vector_type(8)));
typedef _Float16 half2t __attribute__((ext_vector_type(2)));
typedef __fp16   fp16x2 __attribute__((ext_vector_type(2)));
typedef __attribute__((ext_vector_type(4))) float float4v;

__device__ __forceinline__ half2t pkrtz(float a, float b) {
    union { fp16x2 f; half2t h; } cv;
    cv.f = __builtin_amdgcn_cvt_pkrtz(a, b);
    return cv.h;
}

// Fragment-ordered tables: gi = (kt*16 + wt)*64 + lane, lane = quad*16+l15,
// n = 16*wt + l15, j0 = kt*32 + quad*8, p0 = n*256 + j0 + 2:
//   Mtab[gi] = M[n][j0..j0+7] f16
//   Ptab[gi] = P[n][j0..j0+7] f16
//   Jtab[2gi]   = {1/p0, d1, d2, d3}   de = 2*pi*e/(p0*(p0+e))  (psi_e = k*de)
//   Jtab[2gi+1] = {d4, d5, d6, d7}
__global__ void build_tabs(const float* __restrict__ M1, const float* __restrict__ P1,
                           const float* __restrict__ M2, const float* __restrict__ P2,
                           char* __restrict__ ws)
{
    int gid   = blockIdx.x * 256 + threadIdx.x;   // 0..16383
    int layer = gid >> 13;
    int gi    = gid & 8191;
    int idx   = gi >> 6;
    int lane  = gi & 63;
    int kt    = idx >> 4;
    int wt    = idx & 15;
    int l15   = lane & 15, quad = lane >> 4;
    int n     = 16 * wt + l15;
    int j0    = kt * 32 + quad * 8;

    const float* Msrc = layer ? M2 : M1;
    const float* Psrc = layer ? P2 : P1;

    union { half8 h; half2t h2[4]; } mh, ph;
    #pragma unroll
    for (int e = 0; e < 4; ++e) {
        mh.h2[e] = pkrtz(Msrc[(size_t)n * DD + j0 + 2 * e],
                         Msrc[(size_t)n * DD + j0 + 2 * e + 1]);
        ph.h2[e] = pkrtz(Psrc[(size_t)n * DD + j0 + 2 * e],
                         Psrc[(size_t)n * DD + j0 + 2 * e + 1]);
    }
    float p0 = (float)(n * DD + j0 + 2);
    float dv[8];
    dv[0] = 1.0f / p0;                       // iv0 slot
    #pragma unroll
    for (int e = 1; e < 8; ++e)
        dv[e] = TWO_PI * (float)e / (p0 * (p0 + (float)e));   // no cancellation

    char* base = ws + (size_t)layer * LAYER_BYTES;
    ((half8*)base)[gi]              = mh.h;
    ((half8*)(base + PTAB_OFF))[gi] = ph.h;
    float4* jt = (float4*)(base + JTAB_OFF);
    jt[2 * gi]     = make_float4(dv[0], dv[1], dv[2], dv[3]);
    jt[2 * gi + 1] = make_float4(dv[4], dv[5], dv[6], dv[7]);
}

// Block = 512 threads (8 waves), s-pair (s0,s0+1) per block, grid 512 (R10 base).
// Wave w owns n-tiles 2w, 2w+1. Residual in registers.
// Phase B cos: ONE cos + ONE sin per (kt,t) + angle rotation for the other
// 14 values (2nd order, err < f16 quantum); s1 base rotated from s0 by 2*pi/p0.
template<bool TABS>
__global__ __launch_bounds__(512, 4)
void fused_hierddpm(const float* __restrict__ seq,
                    const float* __restrict__ M1, const float* __restrict__ P1,
                    const float* __restrict__ g1, const float* __restrict__ be1,
                    const float* __restrict__ M2, const float* __restrict__ P2,
                    const float* __restrict__ g2, const float* __restrict__ be2,
                    const char* __restrict__ ws,
                    float* __restrict__ out)
{
    __shared__ __align__(16) _Float16 xsb[16][XSTRIDE]; // input / layer-out, f16, A-layout
    __shared__ __align__(16) _Float16 xtb[16][XSTRIDE]; // LN'd xt, f16
    __shared__ float stats[8][16][2];

    const int tid  = threadIdx.x;
    const int w    = tid >> 6;
    const int lane = tid & 63;
    const int l15  = lane & 15;
    const int quad = lane >> 4;
    const int s0   = blockIdx.x * 2;
    const float k0 = (float)s0, k1 = (float)(s0 + 1);

    // ---- stage x into xsb (f16, rows r = sl*8+b), coalesced float4 reads
    {
        const float4* seq4 = (const float4*)seq;
        #pragma unroll
        for (int u = 0; u < 2; ++u) {
            int v  = tid + 512 * u;          // float4 index 0..1023
            int sl = v >> 9;
            int rm = v & 511;
            int b  = rm >> 6, j4 = rm & 63;
            float4 x = seq4[((size_t)b * SS + s0 + sl) * 64 + j4];
            half2t* dst = (half2t*)&xsb[sl * 8 + b][4 * j4];
            dst[0] = pkrtz(x.x, x.y);
            dst[1] = pkrtz(x.z, x.w);
        }
    }

    // ---- residual in registers: res[t][reg] for (sl=quad>>1, b=(quad*4+reg)&7)
    float res[2][4];
    {
        const int sl = quad >> 1;
        #pragma unroll
        for (int t = 0; t < 2; ++t) {
            int col = 16 * (2 * w + t) + l15;
            #pragma unroll
            for (int reg = 0; reg < 4; ++reg) {
                int b = (quad * 4 + reg) & 7;
                res[t][reg] = seq[((size_t)b * SS + s0 + sl) * DD + col];
            }
        }
    }
    __syncthreads();

    #pragma unroll 1
    for (int layer = 0; layer < 2; ++layer) {
        const float* M  = layer ? M2  : M1;
        const float* P  = layer ? P2  : P1;
        const float* g  = layer ? g2  : g1;
        const float* be = layer ? be2 : be1;
        const char*  lbase = ws + (size_t)layer * LAYER_BYTES;
        const half8*  Mtab = (const half8*)lbase;
        const half8*  Ptab = (const half8*)(lbase + PTAB_OFF);
        const float4* Jtab = (const float4*)(lbase + JTAB_OFF);

        // ======== phase A: xt = x @ M^T (f16 MFMA); wave owns n-tiles 2w,2w+1
        float4v acc1[2];
        acc1[0] = (float4v){0.f, 0.f, 0.f, 0.f};
        acc1[1] = (float4v){0.f, 0.f, 0.f, 0.f};

        #pragma unroll 2
        for (int kt = 0; kt < 8; ++kt) {
            half8 a = *(const half8*)&xsb[l15][kt * 32 + quad * 8];
            #pragma unroll
            for (int t = 0; t < 2; ++t) {
                half8 bfrag;
                if (TABS) {
                    bfrag = Mtab[(kt * 16 + 2 * w + t) * 64 + lane];
                } else {
                    int n = 16 * (2 * w + t) + l15;
                    const float4* Mr = (const float4*)M +
                        ((size_t)n * 64 + kt * 8 + quad * 2);
                    float4 m0 = Mr[0], m1 = Mr[1];
                    union { half8 h; half2t h2[4]; } bb;
                    bb.h2[0] = pkrtz(m0.x, m0.y);
                    bb.h2[1] = pkrtz(m0.z, m0.w);
                    bb.h2[2] = pkrtz(m1.x, m1.y);
                    bb.h2[3] = pkrtz(m1.z, m1.w);
                    bfrag = bb.h;
                }
                acc1[t] = __builtin_amdgcn_mfma_f32_16x16x32_f16(a, bfrag, acc1[t], 0, 0, 0);
            }
        }

        // ======== LayerNorm in C-register layout (row m = quad*4+reg)
        {
            #pragma unroll
            for (int reg = 0; reg < 4; ++reg) {
                float sm = acc1[0][reg] + acc1[1][reg];
                float sq = fmaf(acc1[0][reg], acc1[0][reg], acc1[1][reg] * acc1[1][reg]);
                #pragma unroll
                for (int off = 1; off < 16; off <<= 1) {
                    sm += __shfl_xor(sm, off, 64);
                    sq += __shfl_xor(sq, off, 64);
                }
                if (l15 == 0) {
                    stats[w][quad * 4 + reg][0] = sm;
                    stats[w][quad * 4 + reg][1] = sq;
                }
            }
        }
        __syncthreads();
        {
            float mu[4], rs[4];
            #pragma unroll
            for (int reg = 0; reg < 4; ++reg) {
                int m = quad * 4 + reg;
                float sm = 0.f, sq = 0.f;
                #pragma unroll
                for (int ww = 0; ww < 8; ++ww) {
                    sm += stats[ww][m][0];
                    sq += stats[ww][m][1];
                }
                float mm = sm * (1.f / DD);
                mu[reg] = mm;
                rs[reg] = rsqrtf(sq * (1.f / DD) - mm * mm + 1e-5f);
            }
            #pragma unroll
            for (int t = 0; t < 2; ++t) {
                int col = 16 * (2 * w + t) + l15;
                float gv = g[col], bv = be[col];
                #pragma unroll
                for (int reg = 0; reg < 4; ++reg) {
                    float v = fmaf((acc1[t][reg] - mu[reg]) * rs[reg], gv, bv);
                    xtb[quad * 4 + reg][col] = (_Float16)v;
                }
            }
        }
        __syncthreads();   // xtb ready for phase B

        // ======== phase B: Nk = xt @ W_s^T; W = P * cos via angle rotation
        float4v accS[2][2];
        #pragma unroll
        for (int sl = 0; sl < 2; ++sl)
            #pragma unroll
            for (int t = 0; t < 2; ++t) accS[sl][t] = (float4v){0.f, 0.f, 0.f, 0.f};

        #pragma unroll 2
        for (int kt = 0; kt < 8; ++kt) {
            half8 a = *(const half8*)&xtb[l15][kt * 32 + quad * 8];
            #pragma unroll
            for (int t = 0; t < 2; ++t) {
                const int n = 16 * (2 * w + t) + l15;      // W row (output col i)
                const float p0f = (float)(n * DD + kt * 32 + quad * 8 + 2);
                union { half8 h; half2t h2[4]; } pv, b0, b1;

                if (TABS) {
                    int gi = (kt * 16 + 2 * w + t) * 64 + lane;
                    pv.h = Ptab[gi];
                    float4 ja = Jtab[2 * gi], jb = Jtab[2 * gi + 1];
                    const float iv0 = ja.x;
                    // base cos/sin for s0 at element 0 (revolutions input)
                    float f0 = __builtin_amdgcn_fractf(k0 * iv0);
                    float c0 = __builtin_amdgcn_cosf(f0);
                    float s0v = __builtin_amdgcn_sinf(f0);
                    // rotate base to s1: theta1 = theta0 + 2*pi*iv0
                    float dl = TWO_PI * iv0;
                    float c1 = fmaf(-dl, fmaf(0.5f * dl, c0, s0v), c0);
                    float s1v = fmaf(dl, fmaf(-0.5f * dl, s0v, c0), s0v);
                    const float dd[8] = {0.f, ja.y, ja.z, ja.w, jb.x, jb.y, jb.z, jb.w};
                    #pragma unroll
                    for (int ep = 0; ep < 4; ++ep) {
                        float da = dd[2 * ep], db = dd[2 * ep + 1];
                        float pa0 = k0 * da, pb0 = k0 * db;
                        float ce0a = fmaf(pa0, fmaf(-0.5f * pa0, c0, s0v), c0);
                        float ce0b = fmaf(pb0, fmaf(-0.5f * pb0, c0, s0v), c0);
                        float pa1 = k1 * da, pb1 = k1 * db;
                        float ce1a = fmaf(pa1, fmaf(-0.5f * pa1, c1, s1v), c1);
                        float ce1b = fmaf(pb1, fmaf(-0.5f * pb1, c1, s1v), c1);
                        if (p0f < PBMIN) {   // rare lanes (n<=2): exact
                            float ia = __builtin_amdgcn_rcpf(p0f + (float)(2 * ep));
                            float ib = __builtin_amdgcn_rcpf(p0f + (float)(2 * ep + 1));
                            ce0a = __builtin_amdgcn_cosf(__builtin_amdgcn_fractf(k0 * ia));
                            ce0b = __builtin_amdgcn_cosf(__builtin_amdgcn_fractf(k0 * ib));
                            ce1a = __builtin_amdgcn_cosf(__builtin_amdgcn_fractf(k1 * ia));
                            ce1b = __builtin_amdgcn_cosf(__builtin_amdgcn_fractf(k1 * ib));
                        }
                        b0.h2[ep] = pv.h2[ep] * pkrtz(ce0a, ce0b);
                        b1.h2[ep] = pv.h2[ep] * pkrtz(ce1a, ce1b);
                    }
                } else {
                    // exact fallback path (no tables)
                    const float4* Pr = (const float4*)P +
                        ((size_t)n * 64 + kt * 8 + quad * 2);
                    float4 q0 = Pr[0], q1 = Pr[1];
                    pv.h2[0] = pkrtz(q0.x, q0.y);
                    pv.h2[1] = pkrtz(q0.z, q0.w);
                    pv.h2[2] = pkrtz(q1.x, q1.y);
                    pv.h2[3] = pkrtz(q1.z, q1.w);
                    #pragma unroll
                    for (int ep = 0; ep < 4; ++ep) {
                        float ia = __builtin_amdgcn_rcpf(p0f + (float)(2 * ep));
                        float ib = __builtin_amdgcn_rcpf(p0f + (float)(2 * ep + 1));
                        float ce0a = __builtin_amdgcn_cosf(__builtin_amdgcn_fractf(k0 * ia));
                        float ce0b = __builtin_amdgcn_cosf(__builtin_amdgcn_fractf(k0 * ib));
                        float ce1a = __builtin_amdgcn_cosf(__builtin_amdgcn_fractf(k1 * ia));
                        float ce1b = __builtin_amdgcn_cosf(__builtin_amdgcn_fractf(k1 * ib));
                        b0.h2[ep] = pv.h2[ep] * pkrtz(ce0a, ce0b);
                        b1.h2[ep] = pv.h2[ep] * pkrtz(ce1a, ce1b);
                    }
                }
                accS[0][t] = __builtin_amdgcn_mfma_f32_16x16x32_f16(a, b0.h, accS[0][t], 0, 0, 0);
                accS[1][t] = __builtin_amdgcn_mfma_f32_16x16x32_f16(a, b1.h, accS[1][t], 0, 0, 0);
            }
        }

        // ======== epilogue: pick valid s-half per quad, add register residual
        #pragma unroll
        for (int t = 0; t < 2; ++t) {
            int col = 16 * (2 * w + t) + l15;
            float4v av = (quad < 2) ? accS[0][t] : accS[1][t];
            int sl = quad >> 1;
            #pragma unroll
            for (int reg = 0; reg < 4; ++reg) {
                int m = quad * 4 + reg;
                int b = m & 7;
                float val = av[reg] + res[t][reg];
                if (layer == 0) {
                    res[t][reg] = val;             // next layer's residual
                    xsb[m][col] = (_Float16)val;   // next layer's A-matrix
                } else {
                    out[((size_t)b * SS + s0 + sl) * DD + col] = val;
                }
            }
        }
        if (layer == 0) __syncthreads();
    }
}

extern "C" void kernel_launch(void* const* d_in, const int* in_sizes, int n_in,
                              void* d_out, int out_size, void* d_ws, size_t ws_size,
                              hipStream_t stream)
{
    const float* seq = (const float*)d_in[0];
    const float* M1  = (const float*)d_in[1];
    const float* P1  = (const float*)d_in[2];
    const float* g1  = (const float*)d_in[3];
    const float* b1  = (const float*)d_in[4];
    const float* M2  = (const float*)d_in[5];
    const float* P2  = (const float*)d_in[6];
    const float* g2  = (const float*)d_in[7];
    const float* b2  = (const float*)d_in[8];
    float* out = (float*)d_out;

    if (ws_size >= WS_NEEDED) {
        build_tabs<<<64, 256, 0, stream>>>(M1, P1, M2, P2, (char*)d_ws);
        fused_hierddpm<true><<<SS / 2, 512, 0, stream>>>(
            seq, M1, P1, g1, b1, M2, P2, g2, b2, (const char*)d_ws, out);
    } else {
        fused_hierddpm<false><<<SS / 2, 512, 0, stream>>>(
            seq, M1, P1, g1, b1, M2, P2, g2, b2, nullptr, out);
    }
}

// Round 14
// 117.599 us; speedup vs baseline: 1.2603x; 1.0050x over previous
//
#include <hip/hip_runtime.h>

#define DD 256
#define BB 8
#define SS 1024
#define XSTRIDE 264   // f16 elems per LDS row (528 B, 16B-aligned)

// ws layout per layer (bytes): Mtab 131072 | Ptab 131072 | Jtab 262144 = 524288
#define LAYER_BYTES 524288
#define PTAB_OFF    131072
#define JTAB_OFF    262144
#define WS_NEEDED   (2 * LAYER_BYTES)

#define TWO_PI 6.28318530717958647692f

typedef _Float16 half8  __attribute__((ext_vector_type(8)));
typedef _Float16 half2t __attribute__((ext_vector_type(2)));
typedef __fp16   fp16x2 __attribute__((ext_vector_type(2)));
typedef __attribute__((ext_vector_type(4))) float float4v;

__device__ __forceinline__ half2t pkrtz(float a, float b) {
    union { fp16x2 f; half2t h; } cv;
    cv.f = __builtin_amdgcn_cvt_pkrtz(a, b);
    return cv.h;
}

// Fragment-ordered tables: gi = (kt*16 + wt)*64 + lane, lane = quad*16+l15,
// n = 16*wt + l15, j0 = kt*32 + quad*8, p0 = n*256 + j0 + 2:
//   Mtab[gi] = M[n][j0..j0+7] f16
//   Ptab[gi] = P[n][j0..j0+7] f16
//   Jtab[2gi]   = {1/p0, d1, d2, d3}   de = 2*pi*e/(p0*(p0+e))  (psi_e = k*de)
//   Jtab[2gi+1] = {d4, d5, d6, d7}
__global__ void build_tabs(const float* __restrict__ M1, const float* __restrict__ P1,
                           const float* __restrict__ M2, const float* __restrict__ P2,
                           char* __restrict__ ws)
{
    int gid   = blockIdx.x * 256 + threadIdx.x;   // 0..16383
    int layer = gid >> 13;
    int gi    = gid & 8191;
    int idx   = gi >> 6;
    int lane  = gi & 63;
    int kt    = idx >> 4;
    int wt    = idx & 15;
    int l15   = lane & 15, quad = lane >> 4;
    int n     = 16 * wt + l15;
    int j0    = kt * 32 + quad * 8;

    const float* Msrc = layer ? M2 : M1;
    const float* Psrc = layer ? P2 : P1;

    union { half8 h; half2t h2[4]; } mh, ph;
    #pragma unroll
    for (int e = 0; e < 4; ++e) {
        mh.h2[e] = pkrtz(Msrc[(size_t)n * DD + j0 + 2 * e],
                         Msrc[(size_t)n * DD + j0 + 2 * e + 1]);
        ph.h2[e] = pkrtz(Psrc[(size_t)n * DD + j0 + 2 * e],
                         Psrc[(size_t)n * DD + j0 + 2 * e + 1]);
    }
    float p0 = (float)(n * DD + j0 + 2);
    float dv[8];
    dv[0] = 1.0f / p0;                       // iv0 slot
    #pragma unroll
    for (int e = 1; e < 8; ++e)
        dv[e] = TWO_PI * (float)e / (p0 * (p0 + (float)e));   // no cancellation

    char* base = ws + (size_t)layer * LAYER_BYTES;
    ((half8*)base)[gi]              = mh.h;
    ((half8*)(base + PTAB_OFF))[gi] = ph.h;
    float4* jt = (float4*)(base + JTAB_OFF);
    jt[2 * gi]     = make_float4(dv[0], dv[1], dv[2], dv[3]);
    jt[2 * gi + 1] = make_float4(dv[4], dv[5], dv[6], dv[7]);
}

// Block = 512 threads (8 waves), s-pair (s0,s0+1) per block, grid 512.
// Wave w owns n-tiles 2w, 2w+1. Residual in registers.
// Phase B cos: 2 trans (cos+sin) per (kt,t) + 2nd-order angle rotation for
// the other 14 values. Lanes needing exact cos (p0 < ~640) all live in
// (w==0, t==0): that ONE wave takes a scalar-branched exact path; the other
// 31 (kt,t) instances compile rotation-only (no if-conversion).
template<bool TABS>
__global__ __launch_bounds__(512, 4)
void fused_hierddpm(const float* __restrict__ seq,
                    const float* __restrict__ M1, const float* __restrict__ P1,
                    const float* __restrict__ g1, const float* __restrict__ be1,
                    const float* __restrict__ M2, const float* __restrict__ P2,
                    const float* __restrict__ g2, const float* __restrict__ be2,
                    const char* __restrict__ ws,
                    float* __restrict__ out)
{
    __shared__ __align__(16) _Float16 xsb[16][XSTRIDE]; // input / layer-out, f16, A-layout
    __shared__ __align__(16) _Float16 xtb[16][XSTRIDE]; // LN'd xt, f16
    __shared__ float stats[8][16][2];

    const int tid  = threadIdx.x;
    const int w    = tid >> 6;
    const int lane = tid & 63;
    const int l15  = lane & 15;
    const int quad = lane >> 4;
    const int s0   = blockIdx.x * 2;
    const float k0 = (float)s0, k1 = (float)(s0 + 1);
    const int wuni = __builtin_amdgcn_readfirstlane(w);   // scalar wave id

    // ---- stage x into xsb (f16, rows r = sl*8+b), coalesced float4 reads
    {
        const float4* seq4 = (const float4*)seq;
        #pragma unroll
        for (int u = 0; u < 2; ++u) {
            int v  = tid + 512 * u;          // float4 index 0..1023
            int sl = v >> 9;
            int rm = v & 511;
            int b  = rm >> 6, j4 = rm & 63;
            float4 x = seq4[((size_t)b * SS + s0 + sl) * 64 + j4];
            half2t* dst = (half2t*)&xsb[sl * 8 + b][4 * j4];
            dst[0] = pkrtz(x.x, x.y);
            dst[1] = pkrtz(x.z, x.w);
        }
    }

    // ---- residual in registers: res[t][reg] for (sl=quad>>1, b=(quad*4+reg)&7)
    float res[2][4];
    {
        const int sl = quad >> 1;
        #pragma unroll
        for (int t = 0; t < 2; ++t) {
            int col = 16 * (2 * w + t) + l15;
            #pragma unroll
            for (int reg = 0; reg < 4; ++reg) {
                int b = (quad * 4 + reg) & 7;
                res[t][reg] = seq[((size_t)b * SS + s0 + sl) * DD + col];
            }
        }
    }
    __syncthreads();

    #pragma unroll 1
    for (int layer = 0; layer < 2; ++layer) {
        const float* M  = layer ? M2  : M1;
        const float* P  = layer ? P2  : P1;
        const float* g  = layer ? g2  : g1;
        const float* be = layer ? be2 : be1;
        const char*  lbase = ws + (size_t)layer * LAYER_BYTES;
        const half8*  Mtab = (const half8*)lbase;
        const half8*  Ptab = (const half8*)(lbase + PTAB_OFF);
        const float4* Jtab = (const float4*)(lbase + JTAB_OFF);

        // ======== phase A: xt = x @ M^T (f16 MFMA); wave owns n-tiles 2w,2w+1
        float4v acc1[2];
        acc1[0] = (float4v){0.f, 0.f, 0.f, 0.f};
        acc1[1] = (float4v){0.f, 0.f, 0.f, 0.f};

        #pragma unroll 2
        for (int kt = 0; kt < 8; ++kt) {
            half8 a = *(const half8*)&xsb[l15][kt * 32 + quad * 8];
            #pragma unroll
            for (int t = 0; t < 2; ++t) {
                half8 bfrag;
                if (TABS) {
                    bfrag = Mtab[(kt * 16 + 2 * w + t) * 64 + lane];
                } else {
                    int n = 16 * (2 * w + t) + l15;
                    const float4* Mr = (const float4*)M +
                        ((size_t)n * 64 + kt * 8 + quad * 2);
                    float4 m0 = Mr[0], m1 = Mr[1];
                    union { half8 h; half2t h2[4]; } bb;
                    bb.h2[0] = pkrtz(m0.x, m0.y);
                    bb.h2[1] = pkrtz(m0.z, m0.w);
                    bb.h2[2] = pkrtz(m1.x, m1.y);
                    bb.h2[3] = pkrtz(m1.z, m1.w);
                    bfrag = bb.h;
                }
                acc1[t] = __builtin_amdgcn_mfma_f32_16x16x32_f16(a, bfrag, acc1[t], 0, 0, 0);
            }
        }

        // ======== LayerNorm in C-register layout (row m = quad*4+reg)
        {
            #pragma unroll
            for (int reg = 0; reg < 4; ++reg) {
                float sm = acc1[0][reg] + acc1[1][reg];
                float sq = fmaf(acc1[0][reg], acc1[0][reg], acc1[1][reg] * acc1[1][reg]);
                #pragma unroll
                for (int off = 1; off < 16; off <<= 1) {
                    sm += __shfl_xor(sm, off, 64);
                    sq += __shfl_xor(sq, off, 64);
                }
                if (l15 == 0) {
                    stats[w][quad * 4 + reg][0] = sm;
                    stats[w][quad * 4 + reg][1] = sq;
                }
            }
        }
        __syncthreads();
        {
            float mu[4], rs[4];
            #pragma unroll
            for (int reg = 0; reg < 4; ++reg) {
                int m = quad * 4 + reg;
                float sm = 0.f, sq = 0.f;
                #pragma unroll
                for (int ww = 0; ww < 8; ++ww) {
                    sm += stats[ww][m][0];
                    sq += stats[ww][m][1];
                }
                float mm = sm * (1.f / DD);
                mu[reg] = mm;
                rs[reg] = rsqrtf(sq * (1.f / DD) - mm * mm + 1e-5f);
            }
            #pragma unroll
            for (int t = 0; t < 2; ++t) {
                int col = 16 * (2 * w + t) + l15;
                float gv = g[col], bv = be[col];
                #pragma unroll
                for (int reg = 0; reg < 4; ++reg) {
                    float v = fmaf((acc1[t][reg] - mu[reg]) * rs[reg], gv, bv);
                    xtb[quad * 4 + reg][col] = (_Float16)v;
                }
            }
        }
        __syncthreads();   // xtb ready for phase B

        // ======== phase B: Nk = xt @ W_s^T; W = P * cos via angle rotation
        float4v accS[2][2];
        #pragma unroll
        for (int sl = 0; sl < 2; ++sl)
            #pragma unroll
            for (int t = 0; t < 2; ++t) accS[sl][t] = (float4v){0.f, 0.f, 0.f, 0.f};

        #pragma unroll 2
        for (int kt = 0; kt < 8; ++kt) {
            half8 a = *(const half8*)&xtb[l15][kt * 32 + quad * 8];
            #pragma unroll
            for (int t = 0; t < 2; ++t) {
                const int n = 16 * (2 * w + t) + l15;      // W row (output col i)
                const float p0f = (float)(n * DD + kt * 32 + quad * 8 + 2);
                union { half8 h; half2t h2[4]; } pv, b0, b1;

                if (TABS) {
                    int gi = (kt * 16 + 2 * w + t) * 64 + lane;
                    pv.h = Ptab[gi];
                    if (t == 0 && wuni == 0) {
                        // exact path: wave 0 / tile 0 only (contains all p0<640 lanes)
                        #pragma unroll
                        for (int ep = 0; ep < 4; ++ep) {
                            float ia = __builtin_amdgcn_rcpf(p0f + (float)(2 * ep));
                            float ib = __builtin_amdgcn_rcpf(p0f + (float)(2 * ep + 1));
                            float ce0a = __builtin_amdgcn_cosf(__builtin_amdgcn_fractf(k0 * ia));
                            float ce0b = __builtin_amdgcn_cosf(__builtin_amdgcn_fractf(k0 * ib));
                            float ce1a = __builtin_amdgcn_cosf(__builtin_amdgcn_fractf(k1 * ia));
                            float ce1b = __builtin_amdgcn_cosf(__builtin_amdgcn_fractf(k1 * ib));
                            b0.h2[ep] = pv.h2[ep] * pkrtz(ce0a, ce0b);
                            b1.h2[ep] = pv.h2[ep] * pkrtz(ce1a, ce1b);
                        }
                    } else {
                        // rotation path (p0 >= 640 guaranteed for these waves)
                        float4 ja = Jtab[2 * gi], jb = Jtab[2 * gi + 1];
                        const float iv0 = ja.x;
                        float f0  = __builtin_amdgcn_fractf(k0 * iv0);
                        float c0  = __builtin_amdgcn_cosf(f0);
                        float s0v = __builtin_amdgcn_sinf(f0);
                        float dl  = TWO_PI * iv0;     // rotate s0 -> s1 base
                        float c1  = fmaf(-dl, fmaf(0.5f * dl, c0, s0v), c0);
                        float s1v = fmaf(dl, fmaf(-0.5f * dl, s0v, c0), s0v);
                        const float dd[8] = {0.f, ja.y, ja.z, ja.w, jb.x, jb.y, jb.z, jb.w};
                        #pragma unroll
                        for (int ep = 0; ep < 4; ++ep) {
                            float da = dd[2 * ep], db = dd[2 * ep + 1];
                            float pa0 = k0 * da, pb0 = k0 * db;
                            float ce0a = fmaf(pa0, fmaf(-0.5f * pa0, c0, s0v), c0);
                            float ce0b = fmaf(pb0, fmaf(-0.5f * pb0, c0, s0v), c0);
                            float pa1 = k1 * da, pb1 = k1 * db;
                            float ce1a = fmaf(pa1, fmaf(-0.5f * pa1, c1, s1v), c1);
                            float ce1b = fmaf(pb1, fmaf(-0.5f * pb1, c1, s1v), c1);
                            b0.h2[ep] = pv.h2[ep] * pkrtz(ce0a, ce0b);
                            b1.h2[ep] = pv.h2[ep] * pkrtz(ce1a, ce1b);
                        }
                    }
                } else {
                    // exact fallback path (no tables)
                    const float4* Pr = (const float4*)P +
                        ((size_t)n * 64 + kt * 8 + quad * 2);
                    float4 q0 = Pr[0], q1 = Pr[1];
                    pv.h2[0] = pkrtz(q0.x, q0.y);
                    pv.h2[1] = pkrtz(q0.z, q0.w);
                    pv.h2[2] = pkrtz(q1.x, q1.y);
                    pv.h2[3] = pkrtz(q1.z, q1.w);
                    #pragma unroll
                    for (int ep = 0; ep < 4; ++ep) {
                        float ia = __builtin_amdgcn_rcpf(p0f + (float)(2 * ep));
                        float ib = __builtin_amdgcn_rcpf(p0f + (float)(2 * ep + 1));
                        float ce0a = __builtin_amdgcn_cosf(__builtin_amdgcn_fractf(k0 * ia));
                        float ce0b = __builtin_amdgcn_cosf(__builtin_amdgcn_fractf(k0 * ib));
                        float ce1a = __builtin_amdgcn_cosf(__builtin_amdgcn_fractf(k1 * ia));
                        float ce1b = __builtin_amdgcn_cosf(__builtin_amdgcn_fractf(k1 * ib));
                        b0.h2[ep] = pv.h2[ep] * pkrtz(ce0a, ce0b);
                        b1.h2[ep] = pv.h2[ep] * pkrtz(ce1a, ce1b);
                    }
                }
                accS[0][t] = __builtin_amdgcn_mfma_f32_16x16x32_f16(a, b0.h, accS[0][t], 0, 0, 0);
                accS[1][t] = __builtin_amdgcn_mfma_f32_16x16x32_f16(a, b1.h, accS[1][t], 0, 0, 0);
            }
        }

        // ======== epilogue: pick valid s-half per quad, add register residual
        #pragma unroll
        for (int t = 0; t < 2; ++t) {
            int col = 16 * (2 * w + t) + l15;
            float4v av = (quad < 2) ? accS[0][t] : accS[1][t];
            int sl = quad >> 1;
            #pragma unroll
            for (int reg = 0; reg < 4; ++reg) {
                int m = quad * 4 + reg;
                int b = m & 7;
                float val = av[reg] + res[t][reg];
                if (layer == 0) {
                    res[t][reg] = val;             // next layer's residual
                    xsb[m][col] = (_Float16)val;   // next layer's A-matrix
                } else {
                    out[((size_t)b * SS + s0 + sl) * DD + col] = val;
                }
            }
        }
        if (layer == 0) __syncthreads();
    }
}

extern "C" void kernel_launch(void* const* d_in, const int* in_sizes, int n_in,
                              void* d_out, int out_size, void* d_ws, size_t ws_size,
                              hipStream_t stream)
{
    const float* seq = (const float*)d_in[0];
    const float* M1  = (const float*)d_in[1];
    const float* P1  = (const float*)d_in[2];
    const float* g1  = (const float*)d_in[3];
    const float* b1  = (const float*)d_in[4];
    const float* M2  = (const float*)d_in[5];
    const float* P2  = (const float*)d_in[6];
    const float* g2  = (const float*)d_in[7];
    const float* b2  = (const float*)d_in[8];
    float* out = (float*)d_out;

    if (ws_size >= WS_NEEDED) {
        build_tabs<<<64, 256, 0, stream>>>(M1, P1, M2, P2, (char*)d_ws);
        fused_hierddpm<true><<<SS / 2, 512, 0, stream>>>(
            seq, M1, P1, g1, b1, M2, P2, g2, b2, (const char*)d_ws, out);
    } else {
        fused_hierddpm<false><<<SS / 2, 512, 0, stream>>>(
            seq, M1, P1, g1, b1, M2, P2, g2, b2, nullptr, out);
    }
}